// Round 7
// baseline (41.621 us; speedup 1.0000x reference)
//
#include <hip/hip_runtime.h>

// Problem constants (from reference): feat (32, 64, 112, 112) fp32
#define BB 32
#define CC 64
#define HH 112
#define WW 112
#define HW (HH * WW)          // 12544
#define KS 14
#define HP (HH - KS + 1)      // 99
#define WP (WW - KS + 1)      // 99

#define BR 11                 // pooled rows per band
#define NB 9                  // 9 * 11 = 99 = HP exactly
#define MAXH 26               // max staged rows: (BR+2) pooled + 13 halo

// Kernel 1: s2[b,h,w] = (sum_c feat[b,c,h,w])^2, float4-vectorized.
// Measured at ~15 us (R5 ablation) = ~6.7-7 TB/s -> at HBM roofline. Unchanged.
__global__ __launch_bounds__(256) void chan_sum_sq(const float* __restrict__ feat,
                                                   float* __restrict__ s2) {
    const int n4 = BB * (HW / 4);
    int idx4 = blockIdx.x * blockDim.x + threadIdx.x;
    if (idx4 >= n4) return;
    int b = idx4 / (HW / 4);
    int r = idx4 % (HW / 4);
    const float4* base =
        reinterpret_cast<const float4*>(feat) + (size_t)b * CC * (HW / 4) + r;
    float4 acc = make_float4(0.f, 0.f, 0.f, 0.f);
#pragma unroll 16
    for (int c = 0; c < CC; ++c) {
        float4 v = base[(size_t)c * (HW / 4)];
        acc.x += v.x; acc.y += v.y; acc.z += v.z; acc.w += v.w;
    }
    float4 o;
    o.x = acc.x * acc.x;
    o.y = acc.y * acc.y;
    o.z = acc.z * acc.z;
    o.w = acc.w * acc.w;
    reinterpret_cast<float4*>(s2)[idx4] = o;
}

// Kernel 2: band-tiled pooling + sim with LDS staging (R6 version, unchanged).
// ABLATION this round: launched 3x (idempotent) to measure its true marginal
// cost: 2*(pool+oh) = R7_total - R6_total.
__global__ __launch_bounds__(256) void pool_sim_band(const float* __restrict__ s2,
                                                     float* __restrict__ out) {
    __shared__ float srow[MAXH][WW];      // staged s2 rows   (11.6 KB)
    __shared__ float hbuf[MAXH * WP];     // horizontal sums  (10.3 KB)
    __shared__ float pbuf[(BR + 2) * WP]; // pooled rows      ( 5.1 KB)

    const int b = blockIdx.y;
    const int band = blockIdx.x;
    const int r0 = band * BR;
    const int rend = min(r0 + BR, HP);
    const int pstart = max(r0 - 1, 0);
    const int pend = min(r0 + BR + 1, HP);
    const int pcount = pend - pstart;
    const int hcount = pcount + KS - 1;   // <= 26 rows of s2 needed
    const int tid = threadIdx.x;

    const float4* img4 = reinterpret_cast<const float4*>(s2 + (size_t)b * HW);
    for (int i = tid; i < hcount * (WW / 4); i += 256) {
        int hr = i / (WW / 4);
        int c4 = i - hr * (WW / 4);
        reinterpret_cast<float4*>(&srow[hr][0])[c4] = img4[(pstart + hr) * (WW / 4) + c4];
    }
    __syncthreads();

    for (int i = tid; i < hcount * WP; i += 256) {
        int hr = i / WP;
        int wp = i - hr * WP;
        float s = 0.f;
#pragma unroll
        for (int k = 0; k < KS; ++k) s += srow[hr][wp + k];
        hbuf[i] = s;
    }
    __syncthreads();

    for (int i = tid; i < pcount * WP; i += 256) {
        int pr = i / WP;
        int wp = i - pr * WP;
        const float* col = hbuf + pr * WP + wp;
        float s = 0.f;
#pragma unroll
        for (int k = 0; k < KS; ++k) s += col[k * WP];
        pbuf[i] = s * (1.f / (float)(KS * KS));
    }
    __syncthreads();

    float* ob = out + (size_t)b * HP * WP;
    for (int i = tid; i < (rend - r0) * WP; i += 256) {
        int rr = i / WP;
        int wp = i - rr * WP;
        int hp = r0 + rr;
        float center = pbuf[(hp - pstart) * WP + wp];
        float ns = 0.f;
#pragma unroll
        for (int dy = -1; dy <= 1; ++dy) {
#pragma unroll
            for (int dx = -1; dx <= 1; ++dx) {
                if (dy == 0 && dx == 0) continue;
                int y = hp + dy, x = wp + dx;
                if (y >= 0 && y < HP && x >= 0 && x < WP) {
                    ns += pbuf[(y - pstart) * WP + x];
                }
            }
        }
        ob[hp * WP + wp] = (float)(CC * CC) * center * ns;
    }
}

extern "C" void kernel_launch(void* const* d_in, const int* in_sizes, int n_in,
                              void* d_out, int out_size, void* d_ws, size_t ws_size,
                              hipStream_t stream) {
    const float* feat = (const float*)d_in[0];
    float* out = (float*)d_out;
    float* s2 = (float*)d_ws;  // BB*HW = 401,408 floats = 1.6 MB

    {
        int n4 = BB * (HW / 4);
        int blk = 256;
        chan_sum_sq<<<(n4 + blk - 1) / blk, blk, 0, stream>>>(feat, s2);
    }
    {
        dim3 grid(NB, BB);
        // ABLATION: 3 identical launches (idempotent). Marginal cost of two
        // extra = 2*(pool + launch_oh), discriminates fixed-overhead vs
        // slow-pool models.
        pool_sim_band<<<grid, 256, 0, stream>>>(s2, out);
        pool_sim_band<<<grid, 256, 0, stream>>>(s2, out);
        pool_sim_band<<<grid, 256, 0, stream>>>(s2, out);
    }
}

// Round 8
// 25.054 us; speedup vs baseline: 1.6612x; 1.6612x over previous
//
#include <hip/hip_runtime.h>

// Problem constants (from reference): feat (32, 64, 112, 112) fp32
#define BB 32
#define CC 64
#define HH 112
#define WW 112
#define HW (HH * WW)          // 12544
#define KS 14
#define HP (HH - KS + 1)      // 99
#define WP (WW - KS + 1)      // 99

#define BR 5                  // pooled rows per band
#define NB 20                 // ceil(99/5) = 20 bands -> 640 blocks (2.5/CU)
#define MAXP (BR + 2)         // 7 pooled rows incl. halo
#define MAXHC (MAXP + KS - 1) // 20 s2/h-sum rows
#define SW 116                // srow padded width (112 + 4 zero pad), 464B = 16B-aligned stride
#define HBW 100               // hbuf/pbuf padded width, 400B = 16B-aligned stride
#define NG 25                 // groups of 4 outputs per row (25*4 = 100 >= 99)

// Kernel 1: s2[b,h,w] = (sum_c feat[b,c,h,w])^2, float4-vectorized.
// Measured 15.3us (R5 ablation) = ~6.7 TB/s = 94% of fill ceiling. At roofline.
__global__ __launch_bounds__(256) void chan_sum_sq(const float* __restrict__ feat,
                                                   float* __restrict__ s2) {
    const int n4 = BB * (HW / 4);
    int idx4 = blockIdx.x * blockDim.x + threadIdx.x;
    if (idx4 >= n4) return;
    int b = idx4 / (HW / 4);
    int r = idx4 % (HW / 4);
    const float4* base =
        reinterpret_cast<const float4*>(feat) + (size_t)b * CC * (HW / 4) + r;
    float4 acc = make_float4(0.f, 0.f, 0.f, 0.f);
#pragma unroll 16
    for (int c = 0; c < CC; ++c) {
        float4 v = base[(size_t)c * (HW / 4)];
        acc.x += v.x; acc.y += v.y; acc.z += v.z; acc.w += v.w;
    }
    float4 o;
    o.x = acc.x * acc.x;
    o.y = acc.y * acc.y;
    o.z = acc.z * acc.z;
    o.w = acc.w * acc.w;
    reinterpret_cast<float4*>(s2)[idx4] = o;
}

// Kernel 2 v3: R7 ablation -> pool+gap = 7.0us, critical-path bound at
// 1.1 blk/CU with ~140 scalar LDS reads/thread. v3: 640 blocks (BR=5) +
// ds_read_b128 sliding-window h-sums (5 loads / 4 outputs) + float4 v-sums.
__global__ __launch_bounds__(256) void pool_sim_band(const float* __restrict__ s2,
                                                     float* __restrict__ out) {
    __shared__ float srow[MAXHC][SW];   // staged s2 rows   (9.1 KB)
    __shared__ float hbuf[MAXHC][HBW];  // horizontal sums  (8.0 KB)
    __shared__ float pbuf[MAXP][HBW];   // pooled rows      (2.8 KB)

    const int b = blockIdx.y;
    const int band = blockIdx.x;
    const int r0 = band * BR;
    const int rend = min(r0 + BR, HP);
    const int pstart = max(r0 - 1, 0);
    const int pend = min(r0 + BR + 1, HP);
    const int pcount = pend - pstart;
    const int hcount = pcount + KS - 1;   // <= 20 rows of s2 needed
    const int tid = threadIdx.x;

    // P1: stage s2 rows [pstart, pstart+hcount) via float4; zero 4-col pad.
    const float4* img4 = reinterpret_cast<const float4*>(s2 + (size_t)b * HW);
    for (int i = tid; i < hcount * (WW / 4); i += 256) {
        int hr = i / (WW / 4);
        int c4 = i - hr * (WW / 4);
        *reinterpret_cast<float4*>(&srow[hr][c4 * 4]) =
            img4[(pstart + hr) * (WW / 4) + c4];
    }
    if (tid < hcount)
        *reinterpret_cast<float4*>(&srow[tid][WW]) = make_float4(0.f, 0.f, 0.f, 0.f);
    __syncthreads();

    // P2: sliding-window 14-tap h-sums, 4 outputs per unit via 5 ds_read_b128.
    for (int i = tid; i < hcount * NG; i += 256) {
        int hr = i / NG;
        int g = i - hr * NG;
        float f[20];
        *reinterpret_cast<float4*>(&f[0])  = *reinterpret_cast<const float4*>(&srow[hr][g * 4]);
        *reinterpret_cast<float4*>(&f[4])  = *reinterpret_cast<const float4*>(&srow[hr][g * 4 + 4]);
        *reinterpret_cast<float4*>(&f[8])  = *reinterpret_cast<const float4*>(&srow[hr][g * 4 + 8]);
        *reinterpret_cast<float4*>(&f[12]) = *reinterpret_cast<const float4*>(&srow[hr][g * 4 + 12]);
        *reinterpret_cast<float4*>(&f[16]) = *reinterpret_cast<const float4*>(&srow[hr][g * 4 + 16]);
        float s = 0.f;
#pragma unroll
        for (int k = 0; k < KS; ++k) s += f[k];
        float o0 = s;
        float o1 = o0 - f[0] + f[14];
        float o2 = o1 - f[1] + f[15];
        float o3 = o2 - f[2] + f[16];   // wp=g*4+3; slot 99 is pad (zeros), unread
        *reinterpret_cast<float4*>(&hbuf[hr][g * 4]) = make_float4(o0, o1, o2, o3);
    }
    __syncthreads();

    // P3: 14-tap v-sums * 1/196, float4-wide (14 ds_read_b128 per 4 outputs).
    for (int i = tid; i < pcount * NG; i += 256) {
        int pr = i / NG;
        int g = i - pr * NG;
        float4 acc = make_float4(0.f, 0.f, 0.f, 0.f);
#pragma unroll
        for (int k = 0; k < KS; ++k) {
            float4 v = *reinterpret_cast<const float4*>(&hbuf[pr + k][g * 4]);
            acc.x += v.x; acc.y += v.y; acc.z += v.z; acc.w += v.w;
        }
        const float inv = 1.f / (float)(KS * KS);
        acc.x *= inv; acc.y *= inv; acc.z *= inv; acc.w *= inv;
        *reinterpret_cast<float4*>(&pbuf[pr][g * 4]) = acc;
    }
    __syncthreads();

    // P4: sim = C^2 * center * (zero-padded 8-neighbor sum), rows [r0, rend).
    // Guards keep pad col 99 and out-of-image rows/cols excluded.
    float* ob = out + (size_t)b * HP * WP;
    for (int i = tid; i < (rend - r0) * WP; i += 256) {
        int rr = i / WP;
        int wp = i - rr * WP;
        int hp = r0 + rr;
        float center = pbuf[hp - pstart][wp];
        float ns = 0.f;
#pragma unroll
        for (int dy = -1; dy <= 1; ++dy) {
#pragma unroll
            for (int dx = -1; dx <= 1; ++dx) {
                if (dy == 0 && dx == 0) continue;
                int y = hp + dy, x = wp + dx;
                if (y >= 0 && y < HP && x >= 0 && x < WP) {
                    ns += pbuf[y - pstart][x];
                }
            }
        }
        ob[hp * WP + wp] = (float)(CC * CC) * center * ns;
    }
}

extern "C" void kernel_launch(void* const* d_in, const int* in_sizes, int n_in,
                              void* d_out, int out_size, void* d_ws, size_t ws_size,
                              hipStream_t stream) {
    const float* feat = (const float*)d_in[0];
    float* out = (float*)d_out;
    float* s2 = (float*)d_ws;  // BB*HW = 401,408 floats = 1.6 MB

    {
        int n4 = BB * (HW / 4);
        int blk = 256;
        chan_sum_sq<<<(n4 + blk - 1) / blk, blk, 0, stream>>>(feat, s2);
    }
    {
        dim3 grid(NB, BB);
        pool_sim_band<<<grid, 256, 0, stream>>>(s2, out);
    }
}

// Round 9
// 24.159 us; speedup vs baseline: 1.7228x; 1.0370x over previous
//
#include <hip/hip_runtime.h>

// Problem constants (from reference): feat (32, 64, 112, 112) fp32
#define BB 32
#define CC 64
#define HH 112
#define WW 112
#define HW (HH * WW)          // 12544
#define Q4 (HW / 4)           // 3136 quads per channel-image
#define RQ (WW / 4)           // 28 quads per row
#define KS 14
#define HP (HH - KS + 1)      // 99
#define WP (WW - KS + 1)      // 99

#define RPB 8                 // rows per block in kernel 1 (14 blocks/image)
#define SW 116                // LDS row stride: 112 + 4 zero pad (16B aligned)
#define HBW 100               // hbuf row stride: 99 + 1 pad (400B, 16B aligned)
#define NG 25                 // float4 groups per row (25*4 = 100)

#define BR 5                  // pooled rows per band in kernel 2
#define NB 20                 // 20 bands >= 99/5
#define MAXP (BR + 2)         // 7 pooled rows incl halo
#define MAXHC (MAXP + KS - 1) // 20 hbuf rows staged

// Kernel 1: channel-sum + square + horizontal 14-tap sliding sums, fused.
// BW-bound (reads all 103 MB of feat); h-sum VALU+LDS rides under the HBM
// shadow (~4.7x VALU headroom measured from R5 ablation arithmetic).
// Writes hbuf[b][h][wp] = sum_{k<14} (sum_c feat[b,c,h,wp+k])^2.
__global__ __launch_bounds__(256) void chan_hsum(const float* __restrict__ feat,
                                                 float* __restrict__ hbuf) {
    __shared__ float srow[RPB][SW];      // squared channel-sums, 3.7 KB

    const int blk = blockIdx.x;          // 32 images x 14 row-groups
    const int b = blk / (HH / RPB);
    const int h0 = (blk % (HH / RPB)) * RPB;
    const int tid = threadIdx.x;

    // Phase A: thread i < 224 owns quad (h0*RQ + i); sum 64 channels, square.
    if (tid < RPB * RQ) {
        const float4* base = reinterpret_cast<const float4*>(feat)
            + (size_t)b * CC * Q4 + h0 * RQ + tid;
        float4 acc = make_float4(0.f, 0.f, 0.f, 0.f);
#pragma unroll 16
        for (int c = 0; c < CC; ++c) {
            float4 v = base[(size_t)c * Q4];
            acc.x += v.x; acc.y += v.y; acc.z += v.z; acc.w += v.w;
        }
        float4 o;
        o.x = acc.x * acc.x; o.y = acc.y * acc.y;
        o.z = acc.z * acc.z; o.w = acc.w * acc.w;
        int r = tid / RQ, q = tid - r * RQ;
        *reinterpret_cast<float4*>(&srow[r][q * 4]) = o;
    } else if (tid < RPB * RQ + RPB) {
        // zero the 4-col pad of each row
        *reinterpret_cast<float4*>(&srow[tid - RPB * RQ][WW]) =
            make_float4(0.f, 0.f, 0.f, 0.f);
    }
    __syncthreads();

    // Phase B: sliding-window 14-tap h-sums, 4 outputs per item (5 b128 reads).
    float* hb = hbuf + ((size_t)b * HH + h0) * HBW;
    for (int i = tid; i < RPB * NG; i += 256) {
        int r = i / NG;
        int g = i - r * NG;
        float f[20];
        *reinterpret_cast<float4*>(&f[0])  = *reinterpret_cast<const float4*>(&srow[r][g * 4]);
        *reinterpret_cast<float4*>(&f[4])  = *reinterpret_cast<const float4*>(&srow[r][g * 4 + 4]);
        *reinterpret_cast<float4*>(&f[8])  = *reinterpret_cast<const float4*>(&srow[r][g * 4 + 8]);
        *reinterpret_cast<float4*>(&f[12]) = *reinterpret_cast<const float4*>(&srow[r][g * 4 + 12]);
        *reinterpret_cast<float4*>(&f[16]) = *reinterpret_cast<const float4*>(&srow[r][g * 4 + 16]);
        float s = 0.f;
#pragma unroll
        for (int k = 0; k < KS; ++k) s += f[k];
        float o0 = s;
        float o1 = o0 - f[0] + f[14];
        float o2 = o1 - f[1] + f[15];
        float o3 = o2 - f[2] + f[16];    // slot 99 is pad; never read by sim
        *reinterpret_cast<float4*>(&hb[r * HBW + g * 4]) = make_float4(o0, o1, o2, o3);
    }
}

// Kernel 2: vertical 14-tap sums * 1/196 + 8-neighbor sim. Reads hbuf (1.4 MB,
// L2-resident). 640 blocks.
__global__ __launch_bounds__(256) void vsum_sim(const float* __restrict__ hbuf,
                                                float* __restrict__ out) {
    __shared__ float hb[MAXHC][HBW];     // staged h-sum rows (8 KB)
    __shared__ float pbuf[MAXP][HBW];    // pooled rows       (2.8 KB)

    const int b = blockIdx.y;
    const int band = blockIdx.x;
    const int r0 = band * BR;
    const int rend = min(r0 + BR, HP);
    const int pstart = max(r0 - 1, 0);
    const int pend = min(r0 + BR + 1, HP);
    const int pcount = pend - pstart;
    const int hcount = pcount + KS - 1;  // <= 20 hbuf rows
    const int tid = threadIdx.x;

    // Stage hbuf rows [pstart, pstart+hcount)
    const float4* src4 = reinterpret_cast<const float4*>(
        hbuf + ((size_t)b * HH + pstart) * HBW);
    for (int i = tid; i < hcount * NG; i += 256) {
        int hr = i / NG;
        int g = i - hr * NG;
        *reinterpret_cast<float4*>(&hb[hr][g * 4]) = src4[hr * NG + g];
    }
    __syncthreads();

    // Vertical 14-tap sums * 1/196
    for (int i = tid; i < pcount * NG; i += 256) {
        int pr = i / NG;
        int g = i - pr * NG;
        float4 acc = make_float4(0.f, 0.f, 0.f, 0.f);
#pragma unroll
        for (int k = 0; k < KS; ++k) {
            float4 v = *reinterpret_cast<const float4*>(&hb[pr + k][g * 4]);
            acc.x += v.x; acc.y += v.y; acc.z += v.z; acc.w += v.w;
        }
        const float inv = 1.f / (float)(KS * KS);
        acc.x *= inv; acc.y *= inv; acc.z *= inv; acc.w *= inv;
        *reinterpret_cast<float4*>(&pbuf[pr][g * 4]) = acc;
    }
    __syncthreads();

    // sim = C^2 * center * (zero-padded 8-neighbor sum), rows [r0, rend)
    float* ob = out + (size_t)b * HP * WP;
    for (int i = tid; i < (rend - r0) * WP; i += 256) {
        int rr = i / WP;
        int wp = i - rr * WP;
        int hp = r0 + rr;
        float center = pbuf[hp - pstart][wp];
        float ns = 0.f;
#pragma unroll
        for (int dy = -1; dy <= 1; ++dy) {
#pragma unroll
            for (int dx = -1; dx <= 1; ++dx) {
                if (dy == 0 && dx == 0) continue;
                int y = hp + dy, x = wp + dx;
                if (y >= 0 && y < HP && x >= 0 && x < WP) {
                    ns += pbuf[y - pstart][x];
                }
            }
        }
        ob[hp * WP + wp] = (float)(CC * CC) * center * ns;
    }
}

extern "C" void kernel_launch(void* const* d_in, const int* in_sizes, int n_in,
                              void* d_out, int out_size, void* d_ws, size_t ws_size,
                              hipStream_t stream) {
    const float* feat = (const float*)d_in[0];
    float* out = (float*)d_out;
    float* hbuf = (float*)d_ws;  // BB*HH*HBW = 358,400 floats = 1.43 MB

    chan_hsum<<<BB * (HH / RPB), 256, 0, stream>>>(feat, hbuf);
    {
        dim3 grid(NB, BB);
        vsum_sim<<<grid, 256, 0, stream>>>(hbuf, out);
    }
}